// Round 1
// baseline (161.032 us; speedup 1.0000x reference)
//
#include <hip/hip_runtime.h>
#include <math.h>

// Problem constants (B=64, J=17, H=W=128)
#define BJ   1088          // B*J heatmaps per input tensor
#define HW   16384         // 128*128
#define NTH  512           // threads per block (8 waves)
#define NWAVE (NTH / 64)

// One block per heatmap. Stages 64 KB into LDS (one HBM read per element),
// pass 1: block max + first-argmax; pass 2: masked distance sum from LDS.
__global__ __launch_bounds__(NTH) void hm_stats(const float* __restrict__ outp,
                                                const float* __restrict__ tgtp,
                                                float* __restrict__ d)
{
    __shared__ float hm[HW];          // 64 KB -> 2 blocks/CU
    __shared__ float rf[NWAVE];
    __shared__ int   ri[NWAVE];
    __shared__ float rs[NWAVE];
    __shared__ float rc[NWAVE];

    const int map = blockIdx.x;       // [0, 2*BJ): first BJ = output(pred), rest = target(gt)
    const int t   = threadIdx.x;
    const float* __restrict__ src = (map < BJ)
        ? (outp + (size_t)map * HW)
        : (tgtp + (size_t)(map - BJ) * HW);

    const float4* __restrict__ src4 = (const float4*)src;
    float4* hm4 = (float4*)hm;

    // ---- load + local (max, first-idx). base grows monotonically per thread,
    // strict '>' keeps the earliest index within a thread.
    float lmax = -INFINITY;
    int   lidx = 0;
#pragma unroll
    for (int i = 0; i < HW / 4 / NTH; ++i) {          // 8 float4 per thread
        const int v4i = t + i * NTH;
        float4 v = src4[v4i];
        hm4[v4i] = v;
        const int base = v4i << 2;
        if (v.x > lmax) { lmax = v.x; lidx = base;     }
        if (v.y > lmax) { lmax = v.y; lidx = base + 1; }
        if (v.z > lmax) { lmax = v.z; lidx = base + 2; }
        if (v.w > lmax) { lmax = v.w; lidx = base + 3; }
    }

    // ---- wave reduce (max, min idx on ties) — wave = 64 lanes
#pragma unroll
    for (int off = 32; off >= 1; off >>= 1) {
        float ov = __shfl_down(lmax, off, 64);
        int   oi = __shfl_down(lidx, off, 64);
        if (ov > lmax || (ov == lmax && oi < lidx)) { lmax = ov; lidx = oi; }
    }
    const int wave = t >> 6;
    const int lane = t & 63;
    if (lane == 0) { rf[wave] = lmax; ri[wave] = lidx; }
    __syncthreads();
    if (t == 0) {
#pragma unroll
        for (int w = 1; w < NWAVE; ++w) {
            float ov = rf[w]; int oi = ri[w];
            if (ov > lmax || (ov == lmax && oi < lidx)) { lmax = ov; lidx = oi; }
        }
        rf[0] = lmax; ri[0] = lidx;
    }
    __syncthreads();

    const float maxv = rf[0];
    const int   midx = ri[0];
    // reference: ym = idx // H, xm = idx % H  (H==128 stride)
    const float ym  = (float)(midx >> 7);
    const float xm  = (float)(midx & 127);
    const float thv = maxv * 0.5f;

    // ---- pass 2: masked distance sum from LDS (stride-NTH float4, conflict-free)
    float s = 0.0f;
    float c = 0.0f;
#pragma unroll
    for (int i = 0; i < HW / 4 / NTH; ++i) {
        const int v4i = t + i * NTH;
        float4 v = hm4[v4i];
        const int base = v4i << 2;
        // base % 4 == 0 and row width 128 % 4 == 0 -> all 4 elems same row
        const float dy  = (float)(base >> 7) - ym;
        const float dy2 = dy * dy;
        const float cx  = (float)(base & 127) - xm;
        { float dx = cx + 0.0f; if (v.x > thv) { s += sqrtf(dy2 + dx * dx); c += 1.0f; } }
        { float dx = cx + 1.0f; if (v.y > thv) { s += sqrtf(dy2 + dx * dx); c += 1.0f; } }
        { float dx = cx + 2.0f; if (v.z > thv) { s += sqrtf(dy2 + dx * dx); c += 1.0f; } }
        { float dx = cx + 3.0f; if (v.w > thv) { s += sqrtf(dy2 + dx * dx); c += 1.0f; } }
    }

#pragma unroll
    for (int off = 32; off >= 1; off >>= 1) {
        s += __shfl_down(s, off, 64);
        c += __shfl_down(c, off, 64);
    }
    if (lane == 0) { rs[wave] = s; rc[wave] = c; }
    __syncthreads();
    if (t == 0) {
#pragma unroll
        for (int w = 1; w < NWAVE; ++w) { s += rs[w]; c += rc[w]; }
        const float mean = s / fmaxf(c, 1.0f);
        const float dd   = (c > 0.0f) ? (mean / 181.02f) : 1.0f;   // MAX_DIST
        d[map] = (maxv > 0.0f) ? dd : 0.0f;
    }
}

// Single-block final reduction: sum |gt - pred| / J / B
__global__ __launch_bounds__(256) void loss_reduce(const float* __restrict__ d,
                                                   float* __restrict__ out)
{
    __shared__ float rs[4];
    const int t = threadIdx.x;
    float s = 0.0f;
    for (int i = t; i < BJ; i += 256)
        s += fabsf(d[BJ + i] - d[i]);
#pragma unroll
    for (int off = 32; off >= 1; off >>= 1)
        s += __shfl_down(s, off, 64);
    const int wave = t >> 6;
    const int lane = t & 63;
    if (lane == 0) rs[wave] = s;
    __syncthreads();
    if (t == 0) {
        s = rs[0] + rs[1] + rs[2] + rs[3];
        out[0] = s / 17.0f / 64.0f;   // / J / B, matching reference order
    }
}

extern "C" void kernel_launch(void* const* d_in, const int* in_sizes, int n_in,
                              void* d_out, int out_size, void* d_ws, size_t ws_size,
                              hipStream_t stream) {
    const float* outp = (const float*)d_in[0];   // output heatmaps [64,17,128,128] f32
    const float* tgtp = (const float*)d_in[1];   // target heatmaps
    float* d = (float*)d_ws;                     // 2*BJ floats = 8704 B scratch

    hm_stats<<<dim3(2 * BJ), dim3(NTH), 0, stream>>>(outp, tgtp, d);
    loss_reduce<<<dim3(1), dim3(256), 0, stream>>>(d, (float*)d_out);
}

// Round 2
// 160.989 us; speedup vs baseline: 1.0003x; 1.0003x over previous
//
#include <hip/hip_runtime.h>
#include <math.h>

// Problem constants (B=64, J=17, H=W=128)
#define BJ   1088          // B*J heatmaps per input tensor
#define HW   16384         // 128*128
#define NTH  1024          // threads per block (16 waves)
#define EPT  4             // float4 per thread (16 elements, register-resident)
#define NWAVE (NTH / 64)

// Monotonic unsigned key for float bits: orders like float compare.
__device__ __forceinline__ unsigned int ford(unsigned int u) {
    return (u & 0x80000000u) ? ~u : (u | 0x80000000u);
}
__device__ __forceinline__ unsigned int ford_inv(unsigned int o) {
    return (o & 0x80000000u) ? (o & 0x7fffffffu) : ~o;
}

// One 1024-thread block per heatmap. Heatmap lives in REGISTERS (16 elems/thread):
// pass 1 computes block (max, first-argmax) via packed u64 key reduce,
// pass 2 re-reads registers for the masked distance sum. No LDS data staging.
__global__ __launch_bounds__(NTH, 8) void hm_stats(const float* __restrict__ outp,
                                                   const float* __restrict__ tgtp,
                                                   float* __restrict__ d)
{
    __shared__ unsigned long long rkey[NWAVE];
    __shared__ float rs[NWAVE];
    __shared__ float rc[NWAVE];

    const int map = blockIdx.x;       // [0, 2*BJ): first BJ = output(pred), rest = target(gt)
    const int t   = threadIdx.x;
    const float* __restrict__ src = (map < BJ)
        ? (outp + (size_t)map * HW)
        : (tgtp + (size_t)(map - BJ) * HW);
    const float4* __restrict__ src4 = (const float4*)src;

    // ---- pass 1: load to registers + local max/first-idx (idx increases per thread)
    float4 r[EPT];
    float lmax = -INFINITY;
    int   lidx = 0;
#pragma unroll
    for (int i = 0; i < EPT; ++i) {
        const int v4i = t + i * NTH;
        float4 v = src4[v4i];
        r[i] = v;
        const int base = v4i << 2;
        if (v.x > lmax) { lmax = v.x; lidx = base;     }
        if (v.y > lmax) { lmax = v.y; lidx = base + 1; }
        if (v.z > lmax) { lmax = v.z; lidx = base + 2; }
        if (v.w > lmax) { lmax = v.w; lidx = base + 3; }
    }

    // pack (ord(value) << 32) | ~idx : u64 max == (max value, then min idx)
    unsigned long long key =
        ((unsigned long long)ford(__float_as_uint(lmax)) << 32) |
        (unsigned int)~lidx;

    // ---- wave reduce (single u64 max)
#pragma unroll
    for (int off = 32; off >= 1; off >>= 1) {
        unsigned long long ok = __shfl_down(key, off, 64);
        key = (ok > key) ? ok : key;
    }
    const int wave = t >> 6;
    const int lane = t & 63;
    if (lane == 0) rkey[wave] = key;
    __syncthreads();
    if (t == 0) {
#pragma unroll
        for (int w = 1; w < NWAVE; ++w) key = (rkey[w] > key) ? rkey[w] : key;
        rkey[0] = key;
    }
    __syncthreads();

    const unsigned long long bkey = rkey[0];
    const float maxv = __uint_as_float(ford_inv((unsigned int)(bkey >> 32)));
    const int   midx = (int)~(unsigned int)(bkey & 0xffffffffu);
    // reference: ym = idx // H, xm = idx % H  (H==128 stride)
    const float ym  = (float)(midx >> 7);
    const float xm  = (float)(midx & 127);
    const float thv = maxv * 0.5f;

    // ---- pass 2: masked distance sum from REGISTERS (predicated, no branches)
    float s = 0.0f;
    float c = 0.0f;
#pragma unroll
    for (int i = 0; i < EPT; ++i) {
        const int v4i = t + i * NTH;
        float4 v = r[i];
        // all 4 elems share a row (base%4==0, row width 128)
        const float dy  = (float)(v4i >> 5) - ym;
        const float dy2 = dy * dy;
        const float cx  = (float)((v4i << 2) & 127) - xm;
        {
            const float dx = cx;          const float dist = sqrtf(fmaf(dx, dx, dy2));
            const bool m = v.x > thv;     s += m ? dist : 0.0f;  c += m ? 1.0f : 0.0f;
        }
        {
            const float dx = cx + 1.0f;   const float dist = sqrtf(fmaf(dx, dx, dy2));
            const bool m = v.y > thv;     s += m ? dist : 0.0f;  c += m ? 1.0f : 0.0f;
        }
        {
            const float dx = cx + 2.0f;   const float dist = sqrtf(fmaf(dx, dx, dy2));
            const bool m = v.z > thv;     s += m ? dist : 0.0f;  c += m ? 1.0f : 0.0f;
        }
        {
            const float dx = cx + 3.0f;   const float dist = sqrtf(fmaf(dx, dx, dy2));
            const bool m = v.w > thv;     s += m ? dist : 0.0f;  c += m ? 1.0f : 0.0f;
        }
    }

#pragma unroll
    for (int off = 32; off >= 1; off >>= 1) {
        s += __shfl_down(s, off, 64);
        c += __shfl_down(c, off, 64);
    }
    if (lane == 0) { rs[wave] = s; rc[wave] = c; }
    __syncthreads();
    if (t == 0) {
#pragma unroll
        for (int w = 1; w < NWAVE; ++w) { s += rs[w]; c += rc[w]; }
        const float mean = s / fmaxf(c, 1.0f);
        const float dd   = (c > 0.0f) ? (mean / 181.02f) : 1.0f;   // MAX_DIST
        d[map] = (maxv > 0.0f) ? dd : 0.0f;
    }
}

// Single-block final reduction: sum |gt - pred| / J / B
__global__ __launch_bounds__(256) void loss_reduce(const float* __restrict__ d,
                                                   float* __restrict__ out)
{
    __shared__ float rs[4];
    const int t = threadIdx.x;
    float s = 0.0f;
    for (int i = t; i < BJ; i += 256)
        s += fabsf(d[BJ + i] - d[i]);
#pragma unroll
    for (int off = 32; off >= 1; off >>= 1)
        s += __shfl_down(s, off, 64);
    const int wave = t >> 6;
    const int lane = t & 63;
    if (lane == 0) rs[wave] = s;
    __syncthreads();
    if (t == 0) {
        s = rs[0] + rs[1] + rs[2] + rs[3];
        out[0] = s / 17.0f / 64.0f;   // / J / B, matching reference order
    }
}

extern "C" void kernel_launch(void* const* d_in, const int* in_sizes, int n_in,
                              void* d_out, int out_size, void* d_ws, size_t ws_size,
                              hipStream_t stream) {
    const float* outp = (const float*)d_in[0];   // output heatmaps [64,17,128,128] f32
    const float* tgtp = (const float*)d_in[1];   // target heatmaps
    float* d = (float*)d_ws;                     // 2*BJ floats = 8704 B scratch

    hm_stats<<<dim3(2 * BJ), dim3(NTH), 0, stream>>>(outp, tgtp, d);
    loss_reduce<<<dim3(1), dim3(256), 0, stream>>>(d, (float*)d_out);
}